// Round 1
// 531.883 us; speedup vs baseline: 1.3621x; 1.3621x over previous
//
#include <hip/hip_runtime.h>
#include <stdint.h>

#define COLUMNS 1024
#define CPC 16
#define NCELLS 16384
#define SEGS 32
#define SYN 128
#define ACT_TH 10
#define BATCH 4
#define NSEGT (NCELLS*SEGS)       // 524288 segments
#define NPAIR (NSEGT/2)           // 262144 segment-pairs (256 syn each)

#define PG_BLOCKS 1024            // phase_gather grid (4096 waves)

// ---- workspace layout (bytes) ----
#define WS_PRED1 0            // u32[2048]  per-batch pred bitmask (phase1)
#define WS_PRED2 8192         // u32[2048]
#define WS_ACT4P 16384        // u32[2048]  4-bit-per-cell packed prev activity
#define WS_ACT4N 24576        // u32[2048]  4-bit-per-cell packed new activity
#define WS_CNT   32768        // int[8]: num_act[4], num_pred[4]
#define WS_NACT  32800        // int: number of active columns (union over batches)
#define WS_COLS  33024        // int[1024]: compact active-column list
#define WS_CM    65536        // u8[NPAIR*64] connected nibbles (16.8 MB)
#define WS_NEED  (65536 + (size_t)NPAIR * 64)

// Pack prev_active [B][N] (nonzero test) into 4-bit nibbles: word w covers
// cells 8w..8w+7, bit (4*j+b) = batch b active for cell 8w+j.
// Block 8 additionally builds the compact active-column list: a column's
// segments only matter if sdr[b][c] != 0 for some batch (reference masks
// every pred consumer by sdr).
__global__ void build_act4(const uint32_t* __restrict__ prev,
                           const uint32_t* __restrict__ sdr,
                           uint32_t* __restrict__ act4,
                           int* __restrict__ nact,
                           int* __restrict__ cols) {
  if (blockIdx.x == 8) {
    int c = threadIdx.x;  // 256 threads cover 1024 columns
#pragma unroll
    for (int r = 0; r < 4; ++r, c += 256) {
      uint32_t a = sdr[c] | sdr[COLUMNS + c] | sdr[2 * COLUMNS + c] |
                   sdr[3 * COLUMNS + c];
      if (a) {
        int i = atomicAdd(nact, 1);
        cols[i] = c;  // order nondeterministic; consumers are order-invariant
      }
    }
    return;
  }
  int w = blockIdx.x * blockDim.x + threadIdx.x;
  if (w >= NCELLS / 8) return;
  uint32_t word = 0;
#pragma unroll
  for (int j = 0; j < 8; ++j) {
    int cell = w * 8 + j;
#pragma unroll
    for (int b = 0; b < BATCH; ++b)
      word |= (prev[b * NCELLS + cell] != 0u ? 1u : 0u) << (4 * j + b);
  }
  act4[w] = word;
}

// One wave per segment-PAIR per grid-stride step: lane i owns synapses
// 4i..4i+3 of a 256-synapse chunk (seg 2sp: lanes 0..31, seg 2sp+1: lanes
// 32..63). Only pairs belonging to active columns are visited:
// sp = cols[p>>8]*256 + (p&255), p in [0, nact*256).
// Byte-packed per-batch counts, 5-step shfl_xor reduce within 32-lane halves.
template <bool WRITE_CM, bool READ_CM>
__global__ __launch_bounds__(256) void phase_gather(
    const int4* __restrict__ conn4, const float4* __restrict__ vol4,
    const float4* __restrict__ cons4, const uint32_t* __restrict__ g_act4,
    uint32_t* __restrict__ pred, uint8_t* __restrict__ cmb,
    const int* __restrict__ nact, const int* __restrict__ cols) {
  __shared__ uint32_t act4[NCELLS / 8];  // 8 KB nibble activity table
  for (int i = threadIdx.x; i < NCELLS / 8; i += 256) act4[i] = g_act4[i];
  __syncthreads();
  const int lane = threadIdx.x & 63;
  const int gw = blockIdx.x * 4 + (threadIdx.x >> 6);
  const int GW = gridDim.x * 4;
  const int total = nact[0] * 256;  // segment-pairs to process

  // 1-deep software pipeline: registers for the next pair's data
  int p = gw;
  int sp = 0;
  int4 c{};
  float4 v{}, n{};
  uint32_t kb = 0;
  if (p < total) {
    sp = (cols[p >> 8] << 8) | (p & 255);
    size_t pb = (size_t)sp * 64 + lane;
    c = conn4[pb];
    if (READ_CM) kb = cmb[pb];
    else { v = vol4[pb]; n = cons4[pb]; }
  }
  while (p < total) {
    const int spc = sp;
    int4 cc = c;
    float4 cv = v, cn = n;
    uint32_t ck = kb;
    const int pn = p + GW;
    if (pn < total) {
      sp = (cols[pn >> 8] << 8) | (pn & 255);
      size_t nb = (size_t)sp * 64 + lane;
      c = conn4[nb];
      if (READ_CM) kb = cmb[nb];
      else { v = vol4[nb]; n = cons4[nb]; }
    }
    uint32_t k;
    if (READ_CM) {
      k = ck;
    } else {
      k  = (cv.x + cn.x >= 0.8f) ? 1u : 0u;
      k |= (cv.y + cn.y >= 0.8f) ? 2u : 0u;
      k |= (cv.z + cn.z >= 0.8f) ? 4u : 0u;
      k |= (cv.w + cn.w >= 0.8f) ? 8u : 0u;
    }
    if (WRITE_CM) cmb[(size_t)spc * 64 + lane] = (uint8_t)k;

    // gather 4 presynaptic nibbles, accumulate byte-packed per-batch counts
    uint32_t tot = 0;
    {
      int idx;
      uint32_t nib;
      idx = cc.x; nib = (act4[idx >> 3] >> ((idx & 7) * 4)) & 0xFu;
      if (k & 1u) tot += (nib * 0x00204081u) & 0x01010101u;
      idx = cc.y; nib = (act4[idx >> 3] >> ((idx & 7) * 4)) & 0xFu;
      if (k & 2u) tot += (nib * 0x00204081u) & 0x01010101u;
      idx = cc.z; nib = (act4[idx >> 3] >> ((idx & 7) * 4)) & 0xFu;
      if (k & 4u) tot += (nib * 0x00204081u) & 0x01010101u;
      idx = cc.w; nib = (act4[idx >> 3] >> ((idx & 7) * 4)) & 0xFu;
      if (k & 8u) tot += (nib * 0x00204081u) & 0x01010101u;
    }
    // reduce across 32-lane halves (xor masks 1..16 stay within a half)
    tot += (uint32_t)__shfl_xor((int)tot, 1, 64);
    tot += (uint32_t)__shfl_xor((int)tot, 2, 64);
    tot += (uint32_t)__shfl_xor((int)tot, 4, 64);
    tot += (uint32_t)__shfl_xor((int)tot, 8, 64);
    tot += (uint32_t)__shfl_xor((int)tot, 16, 64);

    if ((lane & 31) == 0) {
      uint32_t pf = 0;
      if (((tot >> 0)  & 0xFFu) >= ACT_TH) pf |= 1u;
      if (((tot >> 8)  & 0xFFu) >= ACT_TH) pf |= 2u;
      if (((tot >> 16) & 0xFFu) >= ACT_TH) pf |= 4u;
      if (((tot >> 24) & 0xFFu) >= ACT_TH) pf |= 8u;
      if (pf) {
        int seg = spc * 2 + (lane >> 5);
        int cell = seg >> 5;  // layout [cell][seg]
        uint32_t bit = 1u << (cell & 31);
#pragma unroll
        for (int b = 0; b < BATCH; ++b)
          if ((pf >> b) & 1u)
            atomicOr(&pred[b * (NCELLS / 32) + (cell >> 5)], bit);
      }
    }
    p = pn;
  }
}

// Winner/burst logic per (batch, column); writes new_active floats, packs
// new activity nibbles, accumulates accuracy counters.
__global__ void mid_kernel(const uint32_t* __restrict__ sdr,
                           const uint32_t* __restrict__ pred1,
                           float* __restrict__ out_active,
                           uint32_t* __restrict__ act4n,
                           int* __restrict__ cnts) {
  int tid = blockIdx.x * blockDim.x + threadIdx.x;
  if (tid >= BATCH * COLUMNS) return;
  int b = tid >> 10, c = tid & 1023;
  uint32_t colbits =
      (pred1[b * (NCELLS / 32) + (c >> 1)] >> ((c & 1) * 16)) & 0xFFFFu;
  bool s = sdr[b * COLUMNS + c] != 0u;
  bool has = colbits != 0u;
  uint32_t act = s ? (has ? colbits : 0xFFFFu) : 0u;
  float* o = out_active + (size_t)b * NCELLS + c * CPC;
#pragma unroll
  for (int j = 0; j < CPC; ++j) o[j] = ((act >> j) & 1u) ? 1.0f : 0.0f;
#pragma unroll
  for (int h = 0; h < 2; ++h) {
    uint32_t bits8 = (act >> (8 * h)) & 0xFFu;
    uint32_t sp = 0;
#pragma unroll
    for (int j = 0; j < 8; ++j) sp |= ((bits8 >> j) & 1u) << (4 * j + b);
    if (sp) atomicOr(&act4n[c * 2 + h], sp);
  }
  unsigned long long sb = __ballot(s);
  unsigned long long pb = __ballot(s && has);
  if ((threadIdx.x & 63) == 0) {  // b uniform within a wave (1024 % 64 == 0)
    atomicAdd(&cnts[b], (int)__popcll(sb));
    atomicAdd(&cnts[4 + b], (int)__popcll(pb));
  }
}

// pred_next = pred2 & sdr; also writes accuracy.
__global__ void final_kernel(const uint32_t* __restrict__ sdr,
                             const uint32_t* __restrict__ pred2,
                             const int* __restrict__ cnts,
                             float* __restrict__ out) {
  int tid = blockIdx.x * blockDim.x + threadIdx.x;
  if (tid >= BATCH * COLUMNS) return;
  int b = tid >> 10, c = tid & 1023;
  uint32_t colbits =
      (pred2[b * (NCELLS / 32) + (c >> 1)] >> ((c & 1) * 16)) & 0xFFFFu;
  bool s = sdr[b * COLUMNS + c] != 0u;
  uint32_t pn = s ? colbits : 0u;
  float* o = out + (size_t)BATCH * NCELLS + (size_t)b * NCELLS + c * CPC;
#pragma unroll
  for (int j = 0; j < CPC; ++j) o[j] = ((pn >> j) & 1u) ? 1.0f : 0.0f;
  if (tid < BATCH) {
    int na = cnts[tid], np = cnts[4 + tid];
    out[2 * BATCH * NCELLS + tid] = na > 0 ? (float)np / (float)na : 1.0f;
  }
}

extern "C" void kernel_launch(void* const* d_in, const int* in_sizes, int n_in,
                              void* d_out, int out_size, void* d_ws,
                              size_t ws_size, hipStream_t stream) {
  const uint32_t* sdr = (const uint32_t*)d_in[0];   // bool [4,1024]
  const uint32_t* prev = (const uint32_t*)d_in[1];  // bool [4,16384]
  const int4* conn4 = (const int4*)d_in[2];         // i32 [N,32,128]
  const float4* vol4 = (const float4*)d_in[3];      // f32
  const float4* cons4 = (const float4*)d_in[4];     // f32
  // d_in[5] modulation_signal_batch: unused by reference
  float* out = (float*)d_out;
  char* ws = (char*)d_ws;
  uint32_t* pred1 = (uint32_t*)(ws + WS_PRED1);
  uint32_t* pred2 = (uint32_t*)(ws + WS_PRED2);
  uint32_t* act4p = (uint32_t*)(ws + WS_ACT4P);
  uint32_t* act4n = (uint32_t*)(ws + WS_ACT4N);
  int* cnts = (int*)(ws + WS_CNT);
  int* nact = (int*)(ws + WS_NACT);
  int* cols = (int*)(ws + WS_COLS);
  uint8_t* cmb = (uint8_t*)(ws + WS_CM);
  const bool useCM = ws_size >= WS_NEED;

  hipMemsetAsync(ws, 0, 65536, stream);  // zero pred1/pred2/act4n/cnts/nact
  build_act4<<<9, 256, 0, stream>>>(prev, sdr, act4p, nact, cols);
  if (useCM)
    phase_gather<true, false><<<PG_BLOCKS, 256, 0, stream>>>(
        conn4, vol4, cons4, act4p, pred1, cmb, nact, cols);
  else
    phase_gather<false, false><<<PG_BLOCKS, 256, 0, stream>>>(
        conn4, vol4, cons4, act4p, pred1, cmb, nact, cols);
  mid_kernel<<<16, 256, 0, stream>>>(sdr, pred1, out, act4n, cnts);
  if (useCM)
    phase_gather<false, true><<<PG_BLOCKS, 256, 0, stream>>>(
        conn4, vol4, cons4, act4n, pred2, cmb, nact, cols);
  else
    phase_gather<false, false><<<PG_BLOCKS, 256, 0, stream>>>(
        conn4, vol4, cons4, act4n, pred2, cmb, nact, cols);
  final_kernel<<<16, 256, 0, stream>>>(sdr, pred2, cnts, out);
}

// Round 2
// 528.404 us; speedup vs baseline: 1.3711x; 1.0066x over previous
//
#include <hip/hip_runtime.h>
#include <stdint.h>

#define COLUMNS 1024
#define CPC 16
#define NCELLS 16384
#define SEGS 32
#define SYN 128
#define ACT_TH 10
#define BATCH 4
#define NSEGT (NCELLS*SEGS)       // 524288 segments
#define NPAIR (NSEGT/2)           // 262144 segment-pairs (256 syn each)

#define PG_BLOCKS 1024            // phase_gather grid (4096 waves)

// ---- workspace layout (bytes) ----
#define WS_PRED1 0            // u32[2048]  per-batch pred bitmask (phase1)
#define WS_PRED2 8192         // u32[2048]
#define WS_ACT4P 16384        // u32[2048]  4-bit-per-cell packed prev activity
#define WS_ACT4N 24576        // u32[2048]  4-bit-per-cell packed new activity
#define WS_CNT   32768        // int[8]: num_act[4], num_pred[4]
#define WS_NACT  32800        // int: number of active columns (union over batches)
#define WS_COLS  33024        // int[1024]: compact active-column list
#define WS_CM    65536        // u8[NPAIR*64] connected nibbles (16.8 MB)
#define WS_NEED  (65536 + (size_t)NPAIR * 64)

// Fused setup (replaces hipMemsetAsync + build_act4):
//  blocks 0..7: zero pred1/pred2/act4n(/cnts) AND pack prev_active into 4-bit
//               nibbles (word w covers cells 8w..8w+7, bit (4*j+b) = batch b
//               active for cell 8w+j), with uint4-vectorized prev reads.
//  block 8:     build the compact active-column list with a block-local LDS
//               counter (no pre-zeroed global needed). A column's segments
//               only matter if sdr[b][c] != 0 for some batch (reference masks
//               every pred consumer by sdr).
__global__ void setup_kernel(const uint32_t* __restrict__ prev,
                             const uint32_t* __restrict__ sdr,
                             uint32_t* __restrict__ act4,
                             uint32_t* __restrict__ pred1,
                             uint32_t* __restrict__ pred2,
                             uint32_t* __restrict__ act4n,
                             int* __restrict__ cnts,
                             int* __restrict__ nact,
                             int* __restrict__ cols) {
  if (blockIdx.x == 8) {
    __shared__ int lcnt;
    if (threadIdx.x == 0) lcnt = 0;
    __syncthreads();
    int c = threadIdx.x;  // 256 threads cover 1024 columns
#pragma unroll
    for (int r = 0; r < 4; ++r, c += 256) {
      uint32_t a = sdr[c] | sdr[COLUMNS + c] | sdr[2 * COLUMNS + c] |
                   sdr[3 * COLUMNS + c];
      if (a) {
        int i = atomicAdd(&lcnt, 1);
        cols[i] = c;  // order nondeterministic; consumers are order-invariant
      }
    }
    __syncthreads();
    if (threadIdx.x == 0) nact[0] = lcnt;
    return;
  }
  int w = blockIdx.x * blockDim.x + threadIdx.x;  // 0..2047
  // zero the per-launch accumulators (all are 2048 u32 regions)
  pred1[w] = 0u;
  pred2[w] = 0u;
  act4n[w] = 0u;
  if (w < 8) cnts[w] = 0;
  // pack 8 cells x 4 batches; prev is bool-as-u32, contiguous by cell
  uint32_t word = 0;
#pragma unroll
  for (int b = 0; b < BATCH; ++b) {
    const uint4* p = (const uint4*)(prev + b * NCELLS + w * 8);
    uint4 lo = p[0], hi = p[1];
    uint32_t bits = 0;
    bits |= (lo.x != 0u ? 1u : 0u) << 0;
    bits |= (lo.y != 0u ? 1u : 0u) << 1;
    bits |= (lo.z != 0u ? 1u : 0u) << 2;
    bits |= (lo.w != 0u ? 1u : 0u) << 3;
    bits |= (hi.x != 0u ? 1u : 0u) << 4;
    bits |= (hi.y != 0u ? 1u : 0u) << 5;
    bits |= (hi.z != 0u ? 1u : 0u) << 6;
    bits |= (hi.w != 0u ? 1u : 0u) << 7;
    // spread bit j of `bits` to nibble position 4*j+b
#pragma unroll
    for (int j = 0; j < 8; ++j)
      word |= ((bits >> j) & 1u) << (4 * j + b);
  }
  act4[w] = word;
}

// One wave per segment-PAIR per grid-stride step: lane i owns synapses
// 4i..4i+3 of a 256-synapse chunk (seg 2sp: lanes 0..31, seg 2sp+1: lanes
// 32..63). Only pairs belonging to active columns are visited:
// sp = cols[p>>8]*256 + (p&255), p in [0, nact*256).
// Byte-packed per-batch counts, 5-step shfl_xor reduce within 32-lane halves.
template <bool WRITE_CM, bool READ_CM>
__global__ __launch_bounds__(256) void phase_gather(
    const int4* __restrict__ conn4, const float4* __restrict__ vol4,
    const float4* __restrict__ cons4, const uint32_t* __restrict__ g_act4,
    uint32_t* __restrict__ pred, uint8_t* __restrict__ cmb,
    const int* __restrict__ nact, const int* __restrict__ cols) {
  __shared__ uint32_t act4[NCELLS / 8];  // 8 KB nibble activity table
  for (int i = threadIdx.x; i < NCELLS / 8; i += 256) act4[i] = g_act4[i];
  __syncthreads();
  const int lane = threadIdx.x & 63;
  const int gw = blockIdx.x * 4 + (threadIdx.x >> 6);
  const int GW = gridDim.x * 4;
  const int total = nact[0] * 256;  // segment-pairs to process

  // 1-deep software pipeline: registers for the next pair's data
  int p = gw;
  int sp = 0;
  int4 c{};
  float4 v{}, n{};
  uint32_t kb = 0;
  if (p < total) {
    sp = (cols[p >> 8] << 8) | (p & 255);
    size_t pb = (size_t)sp * 64 + lane;
    c = conn4[pb];
    if (READ_CM) kb = cmb[pb];
    else { v = vol4[pb]; n = cons4[pb]; }
  }
  while (p < total) {
    const int spc = sp;
    int4 cc = c;
    float4 cv = v, cn = n;
    uint32_t ck = kb;
    const int pn = p + GW;
    if (pn < total) {
      sp = (cols[pn >> 8] << 8) | (pn & 255);
      size_t nb = (size_t)sp * 64 + lane;
      c = conn4[nb];
      if (READ_CM) kb = cmb[nb];
      else { v = vol4[nb]; n = cons4[nb]; }
    }
    uint32_t k;
    if (READ_CM) {
      k = ck;
    } else {
      k  = (cv.x + cn.x >= 0.8f) ? 1u : 0u;
      k |= (cv.y + cn.y >= 0.8f) ? 2u : 0u;
      k |= (cv.z + cn.z >= 0.8f) ? 4u : 0u;
      k |= (cv.w + cn.w >= 0.8f) ? 8u : 0u;
    }
    if (WRITE_CM) cmb[(size_t)spc * 64 + lane] = (uint8_t)k;

    // gather 4 presynaptic nibbles, accumulate byte-packed per-batch counts
    uint32_t tot = 0;
    {
      int idx;
      uint32_t nib;
      idx = cc.x; nib = (act4[idx >> 3] >> ((idx & 7) * 4)) & 0xFu;
      if (k & 1u) tot += (nib * 0x00204081u) & 0x01010101u;
      idx = cc.y; nib = (act4[idx >> 3] >> ((idx & 7) * 4)) & 0xFu;
      if (k & 2u) tot += (nib * 0x00204081u) & 0x01010101u;
      idx = cc.z; nib = (act4[idx >> 3] >> ((idx & 7) * 4)) & 0xFu;
      if (k & 4u) tot += (nib * 0x00204081u) & 0x01010101u;
      idx = cc.w; nib = (act4[idx >> 3] >> ((idx & 7) * 4)) & 0xFu;
      if (k & 8u) tot += (nib * 0x00204081u) & 0x01010101u;
    }
    // reduce across 32-lane halves (xor masks 1..16 stay within a half)
    tot += (uint32_t)__shfl_xor((int)tot, 1, 64);
    tot += (uint32_t)__shfl_xor((int)tot, 2, 64);
    tot += (uint32_t)__shfl_xor((int)tot, 4, 64);
    tot += (uint32_t)__shfl_xor((int)tot, 8, 64);
    tot += (uint32_t)__shfl_xor((int)tot, 16, 64);

    if ((lane & 31) == 0) {
      uint32_t pf = 0;
      if (((tot >> 0)  & 0xFFu) >= ACT_TH) pf |= 1u;
      if (((tot >> 8)  & 0xFFu) >= ACT_TH) pf |= 2u;
      if (((tot >> 16) & 0xFFu) >= ACT_TH) pf |= 4u;
      if (((tot >> 24) & 0xFFu) >= ACT_TH) pf |= 8u;
      if (pf) {
        int seg = spc * 2 + (lane >> 5);
        int cell = seg >> 5;  // layout [cell][seg]
        uint32_t bit = 1u << (cell & 31);
#pragma unroll
        for (int b = 0; b < BATCH; ++b)
          if ((pf >> b) & 1u)
            atomicOr(&pred[b * (NCELLS / 32) + (cell >> 5)], bit);
      }
    }
    p = pn;
  }
}

// Winner/burst logic per (batch, column); writes new_active floats, packs
// new activity nibbles, accumulates accuracy counters.
__global__ void mid_kernel(const uint32_t* __restrict__ sdr,
                           const uint32_t* __restrict__ pred1,
                           float* __restrict__ out_active,
                           uint32_t* __restrict__ act4n,
                           int* __restrict__ cnts) {
  int tid = blockIdx.x * blockDim.x + threadIdx.x;
  if (tid >= BATCH * COLUMNS) return;
  int b = tid >> 10, c = tid & 1023;
  uint32_t colbits =
      (pred1[b * (NCELLS / 32) + (c >> 1)] >> ((c & 1) * 16)) & 0xFFFFu;
  bool s = sdr[b * COLUMNS + c] != 0u;
  bool has = colbits != 0u;
  uint32_t act = s ? (has ? colbits : 0xFFFFu) : 0u;
  float* o = out_active + (size_t)b * NCELLS + c * CPC;
#pragma unroll
  for (int j = 0; j < CPC; ++j) o[j] = ((act >> j) & 1u) ? 1.0f : 0.0f;
#pragma unroll
  for (int h = 0; h < 2; ++h) {
    uint32_t bits8 = (act >> (8 * h)) & 0xFFu;
    uint32_t sp = 0;
#pragma unroll
    for (int j = 0; j < 8; ++j) sp |= ((bits8 >> j) & 1u) << (4 * j + b);
    if (sp) atomicOr(&act4n[c * 2 + h], sp);
  }
  unsigned long long sb = __ballot(s);
  unsigned long long pb = __ballot(s && has);
  if ((threadIdx.x & 63) == 0) {  // b uniform within a wave (1024 % 64 == 0)
    atomicAdd(&cnts[b], (int)__popcll(sb));
    atomicAdd(&cnts[4 + b], (int)__popcll(pb));
  }
}

// pred_next = pred2 & sdr; also writes accuracy.
__global__ void final_kernel(const uint32_t* __restrict__ sdr,
                             const uint32_t* __restrict__ pred2,
                             const int* __restrict__ cnts,
                             float* __restrict__ out) {
  int tid = blockIdx.x * blockDim.x + threadIdx.x;
  if (tid >= BATCH * COLUMNS) return;
  int b = tid >> 10, c = tid & 1023;
  uint32_t colbits =
      (pred2[b * (NCELLS / 32) + (c >> 1)] >> ((c & 1) * 16)) & 0xFFFFu;
  bool s = sdr[b * COLUMNS + c] != 0u;
  uint32_t pn = s ? colbits : 0u;
  float* o = out + (size_t)BATCH * NCELLS + (size_t)b * NCELLS + c * CPC;
#pragma unroll
  for (int j = 0; j < CPC; ++j) o[j] = ((pn >> j) & 1u) ? 1.0f : 0.0f;
  if (tid < BATCH) {
    int na = cnts[tid], np = cnts[4 + tid];
    out[2 * BATCH * NCELLS + tid] = na > 0 ? (float)np / (float)na : 1.0f;
  }
}

extern "C" void kernel_launch(void* const* d_in, const int* in_sizes, int n_in,
                              void* d_out, int out_size, void* d_ws,
                              size_t ws_size, hipStream_t stream) {
  const uint32_t* sdr = (const uint32_t*)d_in[0];   // bool [4,1024]
  const uint32_t* prev = (const uint32_t*)d_in[1];  // bool [4,16384]
  const int4* conn4 = (const int4*)d_in[2];         // i32 [N,32,128]
  const float4* vol4 = (const float4*)d_in[3];      // f32
  const float4* cons4 = (const float4*)d_in[4];     // f32
  // d_in[5] modulation_signal_batch: unused by reference
  float* out = (float*)d_out;
  char* ws = (char*)d_ws;
  uint32_t* pred1 = (uint32_t*)(ws + WS_PRED1);
  uint32_t* pred2 = (uint32_t*)(ws + WS_PRED2);
  uint32_t* act4p = (uint32_t*)(ws + WS_ACT4P);
  uint32_t* act4n = (uint32_t*)(ws + WS_ACT4N);
  int* cnts = (int*)(ws + WS_CNT);
  int* nact = (int*)(ws + WS_NACT);
  int* cols = (int*)(ws + WS_COLS);
  uint8_t* cmb = (uint8_t*)(ws + WS_CM);
  const bool useCM = ws_size >= WS_NEED;

  setup_kernel<<<9, 256, 0, stream>>>(prev, sdr, act4p, pred1, pred2, act4n,
                                      cnts, nact, cols);
  if (useCM)
    phase_gather<true, false><<<PG_BLOCKS, 256, 0, stream>>>(
        conn4, vol4, cons4, act4p, pred1, cmb, nact, cols);
  else
    phase_gather<false, false><<<PG_BLOCKS, 256, 0, stream>>>(
        conn4, vol4, cons4, act4p, pred1, cmb, nact, cols);
  mid_kernel<<<16, 256, 0, stream>>>(sdr, pred1, out, act4n, cnts);
  if (useCM)
    phase_gather<false, true><<<PG_BLOCKS, 256, 0, stream>>>(
        conn4, vol4, cons4, act4n, pred2, cmb, nact, cols);
  else
    phase_gather<false, false><<<PG_BLOCKS, 256, 0, stream>>>(
        conn4, vol4, cons4, act4n, pred2, cmb, nact, cols);
  final_kernel<<<16, 256, 0, stream>>>(sdr, pred2, cnts, out);
}